// Round 2
// baseline (87.646 us; speedup 1.0000x reference)
//
#include <hip/hip_runtime.h>

#define BN 200
#define KK 32
#define HH 138
#define WW 138
#define HO 550
#define WO 550
#define NPIX (HH*WW)      // 19044
#define NOUT (HO*WO)      // 302500
#define EPS 1e-6f
#define LOG2E 1.4426950408889634f

#if __has_builtin(__builtin_amdgcn_rcpf)
#define RCP(x) __builtin_amdgcn_rcpf(x)
#else
#define RCP(x) (1.0f/(x))
#endif
#if __has_builtin(__builtin_amdgcn_exp2f)
#define EXP2(x) __builtin_amdgcn_exp2f(x)
#else
#define EXP2(x) exp2f(x)
#endif

// ---------------- Kernel 0: separable gaussian tables ---------------------
// gx[b][n][w] = exp(-0.5*((x_w-cx)/sx)^2) * conf[b][n]
// gy[b][n][h] = exp(-0.5*((y_h-cy)/sy)^2)          (H==W so one coord loop)
__global__ __launch_bounds__(256) void k_tables(
    const float* __restrict__ loc,    // [B,200,4]
    const float* __restrict__ conf,   // [B,200]
    float* __restrict__ gx,           // [B,200,138]
    float* __restrict__ gy)           // [B,200,138]
{
    const int i = blockIdx.x * 256 + threadIdx.x;   // over B*N*138
    if (i >= 8 * BN * WW) return;
    const int bn = i / WW;
    const int c  = i - bn * WW;
    const float4 l = ((const float4*)loc)[bn];
    const float v = (c + 0.5f) * (1.0f / WW);
    const float dx = (v - l.x) * RCP(l.z);
    const float dy = (v - l.y) * RCP(l.w);
    gx[i] = EXP2(-0.5f * LOG2E * dx * dx) * conf[bn];
    gy[i] = EXP2(-0.5f * LOG2E * dy * dy);
}

// ---------------- Kernel 1: fused sigmoid(proto.mask)*gx*gy -> final_conf
template<bool TAB>
__global__ __launch_bounds__(128) void k_finalconf(
    const float* __restrict__ loc,    // [B,200,4]
    const float* __restrict__ conf,   // [B,200]
    const float* __restrict__ mask,   // [B,200,32]
    const float* __restrict__ proto,  // [B,138,138,32]
    const float* __restrict__ gx,
    const float* __restrict__ gy,
    float* __restrict__ fconf)        // [B,138,138]
{
    const int b   = blockIdx.y;
    const int tid = threadIdx.x;

    __shared__ float sm_mask[BN * KK];
    __shared__ float sm_cx[BN], sm_cy[BN], sm_isx[BN], sm_isy[BN], sm_cf[BN];

    const float4* mb = (const float4*)(mask + (size_t)b * BN * KK);
    for (int i = tid; i < BN * KK / 4; i += 128)
        ((float4*)sm_mask)[i] = mb[i];

    if (!TAB) {
        const float4* lb = (const float4*)(loc + (size_t)b * BN * 4);
        const float*  cb = conf + (size_t)b * BN;
        for (int n = tid; n < BN; n += 128) {
            float4 l = lb[n];
            sm_cx[n]  = l.x;
            sm_cy[n]  = l.y;
            sm_isx[n] = RCP(l.z);
            sm_isy[n] = RCP(l.w);
            sm_cf[n]  = cb[n];
        }
    }
    __syncthreads();

    const int pix = blockIdx.x * 128 + tid;
    if (pix >= NPIX) return;
    const int h = pix / WW;
    const int w = pix - h * WW;
    const float x = (w + 0.5f) * (1.0f / WW);
    const float y = (h + 0.5f) * (1.0f / HH);

    float4 p[8];
    const float4* pb = (const float4*)(proto + ((size_t)b * NPIX + pix) * KK);
#pragma unroll
    for (int i = 0; i < 8; ++i) p[i] = pb[i];

    const float* gxp = gx + (size_t)b * BN * WW + w;
    const float* gyp = gy + (size_t)b * BN * WW + h;

    float sum1 = 0.0f, sum2 = 0.0f;
#pragma unroll 2
    for (int n = 0; n < BN; ++n) {
        const float4* m4 = (const float4*)(sm_mask + n * KK);
        // 4 independent accumulator chains (ILP) over K=32
        float s0 = 0.0f, s1 = 0.0f, s2 = 0.0f, s3 = 0.0f;
#pragma unroll
        for (int i = 0; i < 8; i += 4) {
            float4 ma = m4[i], mbv = m4[i+1], mcv = m4[i+2], mdv = m4[i+3];
            s0 = fmaf(p[i  ].x, ma.x,  fmaf(p[i  ].y, ma.y,  fmaf(p[i  ].z, ma.z,  fmaf(p[i  ].w, ma.w,  s0))));
            s1 = fmaf(p[i+1].x, mbv.x, fmaf(p[i+1].y, mbv.y, fmaf(p[i+1].z, mbv.z, fmaf(p[i+1].w, mbv.w, s1))));
            s2 = fmaf(p[i+2].x, mcv.x, fmaf(p[i+2].y, mcv.y, fmaf(p[i+2].z, mcv.z, fmaf(p[i+2].w, mcv.w, s2))));
            s3 = fmaf(p[i+3].x, mdv.x, fmaf(p[i+3].y, mdv.y, fmaf(p[i+3].z, mdv.z, fmaf(p[i+3].w, mdv.w, s3))));
        }
        const float s = (s0 + s1) + (s2 + s3);
        // sigmoid(s) = 1/(1+exp2(-s*log2e))
        const float t = EXP2(-LOG2E * s);
        const float a = RCP(1.0f + t);

        float mc;
        if (TAB) {
            const float G = gxp[n * WW] * gyp[n * WW];   // conf folded into gx
            mc = a * G;
        } else {
            const float dx = (x - sm_cx[n]) * sm_isx[n];
            const float dy = (y - sm_cy[n]) * sm_isy[n];
            const float g  = EXP2(-0.5f * LOG2E * fmaf(dx, dx, dy * dy));
            mc = a * g * sm_cf[n];
        }
        sum1 += mc;
        sum2 = fmaf(mc, mc, sum2);
    }
    fconf[(size_t)b * NPIX + pix] = 1.0f - sum2 * RCP(sum1 + EPS);
}

// ---------------- Kernel 2: bilinear upsample + weighted variance --------
__global__ __launch_bounds__(256) void k_variance(
    const float* __restrict__ orig,   // [B,3,550,550]
    const float* __restrict__ fconf,  // [B,138,138]
    float* __restrict__ partial)      // [gridDim.x]
{
    const int idx = blockIdx.x * 256 + threadIdx.x;
    float local = 0.0f;

    if (idx < NOUT) {
        const int yo = idx / WO;
        const int xo = idx - yo * WO;
        const float scale = 138.0f / 550.0f;
        float fy = (yo + 0.5f) * scale - 0.5f;
        float fx = (xo + 0.5f) * scale - 0.5f;
        float fy0 = floorf(fy), fx0 = floorf(fx);
        float wy = fy - fy0, wx = fx - fx0;
        int y0 = max(0, min(HH - 1, (int)fy0));
        int y1 = max(0, min(HH - 1, (int)fy0 + 1));
        int x0 = max(0, min(WW - 1, (int)fx0));
        int x1 = max(0, min(WW - 1, (int)fx0 + 1));

        float R[8];
        float T = 0.0f;
#pragma unroll
        for (int b = 0; b < 8; ++b) {
            const float* F = fconf + (size_t)b * NPIX;
            float v00 = F[y0 * WW + x0], v01 = F[y0 * WW + x1];
            float v10 = F[y1 * WW + x0], v11 = F[y1 * WW + x1];
            float v0 = v00 + wx * (v01 - v00);
            float v1 = v10 + wx * (v11 - v10);
            R[b] = v0 + wy * (v1 - v0);
            T += R[b];
        }
        const float invT = RCP(T + EPS);

#pragma unroll
        for (int c = 0; c < 3; ++c) {
            float o[8];
            float M = 0.0f;
#pragma unroll
            for (int b = 0; b < 8; ++b) {
                o[b] = orig[((size_t)b * 3 + c) * NOUT + idx];
                M = fmaf(o[b], R[b], M);
            }
            float s = 0.0f;
#pragma unroll
            for (int b = 0; b < 8; ++b) {
                float d = o[b] - M;
                s = fmaf(d * d, R[b], s);
            }
            local += s * invT;
        }
    }

    __shared__ float red[4];
    const int lane = threadIdx.x & 63;
    const int wid  = threadIdx.x >> 6;
#pragma unroll
    for (int off = 32; off > 0; off >>= 1)
        local += __shfl_down(local, off);
    if (lane == 0) red[wid] = local;
    __syncthreads();
    if (threadIdx.x == 0)
        partial[blockIdx.x] = (red[0] + red[1]) + (red[2] + red[3]);
}

// ---------------- Kernel 3: deterministic final reduce -------------------
__global__ __launch_bounds__(256) void k_reduce(
    const float* __restrict__ partial, int n, float* __restrict__ out)
{
    float s = 0.0f;
    for (int i = threadIdx.x; i < n; i += 256) s += partial[i];
    __shared__ float red[4];
    const int lane = threadIdx.x & 63;
    const int wid  = threadIdx.x >> 6;
#pragma unroll
    for (int off = 32; off > 0; off >>= 1)
        s += __shfl_down(s, off);
    if (lane == 0) red[wid] = s;
    __syncthreads();
    if (threadIdx.x == 0)
        out[0] = (red[0] + red[1]) + (red[2] + red[3]);
}

extern "C" void kernel_launch(void* const* d_in, const int* in_sizes, int n_in,
                              void* d_out, int out_size, void* d_ws, size_t ws_size,
                              hipStream_t stream) {
    const float* original = (const float*)d_in[0];  // [8,3,550,550]
    const float* loc      = (const float*)d_in[1];  // [8,200,4]
    const float* conf     = (const float*)d_in[2];  // [8,200]
    const float* mask     = (const float*)d_in[3];  // [8,200,32]
    const float* proto    = (const float*)d_in[4];  // [8,138,138,32]
    float* out = (float*)d_out;

    const int nb2 = (NOUT + 255) / 256;             // 1182

    const size_t sz_fconf = (size_t)8 * NPIX * sizeof(float);      // 609,408
    const size_t sz_g     = (size_t)8 * BN * WW * sizeof(float);   // 883,200
    const size_t need_tab = sz_fconf + 2 * sz_g + (size_t)nb2 * sizeof(float);

    float* fconf = (float*)d_ws;
    dim3 g1((NPIX + 127) / 128, 8);

    if (ws_size >= need_tab) {
        float* gx      = (float*)((char*)d_ws + sz_fconf);
        float* gy      = (float*)((char*)d_ws + sz_fconf + sz_g);
        float* partial = (float*)((char*)d_ws + sz_fconf + 2 * sz_g);

        k_tables<<<(8 * BN * WW + 255) / 256, 256, 0, stream>>>(loc, conf, gx, gy);
        k_finalconf<true><<<g1, 128, 0, stream>>>(loc, conf, mask, proto, gx, gy, fconf);
        k_variance<<<nb2, 256, 0, stream>>>(original, fconf, partial);
        k_reduce<<<1, 256, 0, stream>>>(partial, nb2, out);
    } else {
        float* partial = (float*)((char*)d_ws + sz_fconf);
        k_finalconf<false><<<g1, 128, 0, stream>>>(loc, conf, mask, proto, fconf, fconf, fconf);
        k_variance<<<nb2, 256, 0, stream>>>(original, fconf, partial);
        k_reduce<<<1, 256, 0, stream>>>(partial, nb2, out);
    }
}

// Round 3
// 41.730 us; speedup vs baseline: 2.1003x; 2.1003x over previous
//
#include <hip/hip_runtime.h>
#include <hip/hip_bf16.h>

#define BN 200
#define KK 32
#define NT 13          // 13 n-tiles of 16 priors = 208 (padded, cf=0 for tail)
#define HH 138
#define WW 138
#define HO 550
#define WO 550
#define NPIX (HH*WW)      // 19044
#define NOUT (HO*WO)      // 302500
#define EPS 1e-6f
#define LOG2E 1.4426950408889634f

#if __has_builtin(__builtin_amdgcn_rcpf)
#define RCP(x) __builtin_amdgcn_rcpf(x)
#else
#define RCP(x) (1.0f/(x))
#endif
#if __has_builtin(__builtin_amdgcn_exp2f)
#define EXP2(x) __builtin_amdgcn_exp2f(x)
#else
#define EXP2(x) exp2f(x)
#endif

typedef __attribute__((ext_vector_type(8))) short short8v;   // 8 bf16 (4 VGPRs)
typedef __attribute__((ext_vector_type(4))) float f32x4;     // MFMA acc

static __device__ inline short f2bf(float x) {
    __hip_bfloat16 h = __float2bfloat16(x);   // RNE
    return *reinterpret_cast<short*>(&h);
}

// ---------------- Kernel 1: MFMA sigmoid(proto.mask) * gauss * conf ------
// block = 256 threads = 4 waves; each wave owns 16 pixels; block owns 64.
__global__ __launch_bounds__(256) void k_finalconf(
    const float* __restrict__ loc,    // [B,200,4] (cx,cy,sx,sy)
    const float* __restrict__ conf,   // [B,200]
    const float* __restrict__ mask,   // [B,200,32]
    const float* __restrict__ proto,  // [B,138,138,32]
    float* __restrict__ fconf)        // [B,138,138]
{
    const int b   = blockIdx.y;
    const int tid = threadIdx.x;

    // B-fragments for all 13 n-tiles, MFMA lane order:
    // lane l holds B[k=8*(l>>4)+j][col=l&15], j=0..7 contiguous.
    __shared__ short sm_bfrag[NT * 64 * 8];              // 13312 B
    __shared__ float sm_cx[NT*16], sm_cy[NT*16], sm_isx[NT*16], sm_isy[NT*16], sm_cf[NT*16];

    for (int idx = tid; idx < NT * 64; idx += 256) {
        const int t  = idx >> 6;
        const int l  = idx & 63;
        const int n  = t * 16 + (l & 15);
        const int k0 = (l >> 4) * 8;
        short8v v;
#pragma unroll
        for (int j = 0; j < 8; ++j) v[j] = 0;
        if (n < BN) {
            const float4* src = (const float4*)(mask + ((size_t)b * BN + n) * KK + k0);
            float4 u0 = src[0], u1 = src[1];
            v[0] = f2bf(u0.x); v[1] = f2bf(u0.y); v[2] = f2bf(u0.z); v[3] = f2bf(u0.w);
            v[4] = f2bf(u1.x); v[5] = f2bf(u1.y); v[6] = f2bf(u1.z); v[7] = f2bf(u1.w);
        }
        *(short8v*)&sm_bfrag[idx * 8] = v;
    }
    for (int n = tid; n < NT * 16; n += 256) {
        if (n < BN) {
            float4 l4 = ((const float4*)(loc + (size_t)b * BN * 4))[n];
            sm_cx[n] = l4.x; sm_cy[n] = l4.y;
            sm_isx[n] = RCP(l4.z); sm_isy[n] = RCP(l4.w);
            sm_cf[n] = conf[(size_t)b * BN + n];
        } else {
            sm_cx[n] = 0.5f; sm_cy[n] = 0.5f; sm_isx[n] = 1.0f; sm_isy[n] = 1.0f;
            sm_cf[n] = 0.0f;
        }
    }
    __syncthreads();

    const int wid  = tid >> 6;
    const int lane = tid & 63;
    const int mbase = blockIdx.x * 64 + wid * 16;

    // A-fragment: lane l holds proto[pix = mbase+(l&15)][k = 8*(l>>4)+j]
    int pa = mbase + (lane & 15);
    if (pa >= NPIX) pa = NPIX - 1;                    // clamped (OOB rows unused)
    const int ka = (lane >> 4) * 8;
    const float4* asrc = (const float4*)(proto + ((size_t)b * NPIX + pa) * KK + ka);
    float4 a0 = asrc[0], a1 = asrc[1];
    short8v afrag;
    afrag[0] = f2bf(a0.x); afrag[1] = f2bf(a0.y); afrag[2] = f2bf(a0.z); afrag[3] = f2bf(a0.w);
    afrag[4] = f2bf(a1.x); afrag[5] = f2bf(a1.y); afrag[6] = f2bf(a1.z); afrag[7] = f2bf(a1.w);

    // C rows this lane accumulates: pixel p_r = mbase + (lane>>4)*4 + r
    float xr[4], yr[4];
    int   pr[4];
#pragma unroll
    for (int r = 0; r < 4; ++r) {
        int p = mbase + (lane >> 4) * 4 + r;
        pr[r] = p;
        int pc = p < NPIX ? p : NPIX - 1;
        int h = pc / WW, w = pc - h * WW;
        xr[r] = (w + 0.5f) * (1.0f / WW);
        yr[r] = (h + 0.5f) * (1.0f / HH);
    }

    float sum1[4] = {0.f, 0.f, 0.f, 0.f};
    float sum2[4] = {0.f, 0.f, 0.f, 0.f};

#pragma unroll 2
    for (int t = 0; t < NT; ++t) {
        short8v bfrag = *(const short8v*)&sm_bfrag[(t * 64 + lane) * 8];
        f32x4 c = {0.f, 0.f, 0.f, 0.f};
        c = __builtin_amdgcn_mfma_f32_16x16x32_bf16(afrag, bfrag, c, 0, 0, 0);

        const int n = t * 16 + (lane & 15);
        const float cx = sm_cx[n], cy = sm_cy[n];
        const float isx = sm_isx[n], isy = sm_isy[n], cf = sm_cf[n];
#pragma unroll
        for (int r = 0; r < 4; ++r) {
            const float s  = c[r];
            const float tt = EXP2(-LOG2E * s);              // exp(-s)
            const float dx = (xr[r] - cx) * isx;
            const float dy = (yr[r] - cy) * isy;
            const float g  = EXP2(-0.5f * LOG2E * fmaf(dx, dx, dy * dy));
            const float mc = g * cf * RCP(1.0f + tt);
            sum1[r] += mc;
            sum2[r] = fmaf(mc, mc, sum2[r]);
        }
    }

    // reduce over the 16 prior-columns (lane&15 butterfly)
#pragma unroll
    for (int m = 1; m < 16; m <<= 1) {
#pragma unroll
        for (int r = 0; r < 4; ++r) {
            sum1[r] += __shfl_xor(sum1[r], m);
            sum2[r] += __shfl_xor(sum2[r], m);
        }
    }

    const int rsel = lane & 15;
#pragma unroll
    for (int r = 0; r < 4; ++r) {
        if (rsel == r && pr[r] < NPIX)
            fconf[(size_t)b * NPIX + pr[r]] = 1.0f - sum2[r] * RCP(sum1[r] + EPS);
    }
}

// ---------------- Kernel 2: bilinear upsample + weighted variance --------
__global__ __launch_bounds__(256) void k_variance(
    const float* __restrict__ orig,   // [B,3,550,550]
    const float* __restrict__ fconf,  // [B,138,138]
    float* __restrict__ partial)      // [gridDim.x]
{
    const int idx = blockIdx.x * 256 + threadIdx.x;
    float local = 0.0f;

    if (idx < NOUT) {
        const int yo = idx / WO;
        const int xo = idx - yo * WO;
        const float scale = 138.0f / 550.0f;
        float fy = (yo + 0.5f) * scale - 0.5f;
        float fx = (xo + 0.5f) * scale - 0.5f;
        float fy0 = floorf(fy), fx0 = floorf(fx);
        float wy = fy - fy0, wx = fx - fx0;
        int y0 = max(0, min(HH - 1, (int)fy0));
        int y1 = max(0, min(HH - 1, (int)fy0 + 1));
        int x0 = max(0, min(WW - 1, (int)fx0));
        int x1 = max(0, min(WW - 1, (int)fx0 + 1));

        float R[8];
        float T = 0.0f;
#pragma unroll
        for (int b = 0; b < 8; ++b) {
            const float* F = fconf + (size_t)b * NPIX;
            float v00 = F[y0 * WW + x0], v01 = F[y0 * WW + x1];
            float v10 = F[y1 * WW + x0], v11 = F[y1 * WW + x1];
            float v0 = v00 + wx * (v01 - v00);
            float v1 = v10 + wx * (v11 - v10);
            R[b] = v0 + wy * (v1 - v0);
            T += R[b];
        }
        const float invT = RCP(T + EPS);

#pragma unroll
        for (int c = 0; c < 3; ++c) {
            float o[8];
            float M = 0.0f;
#pragma unroll
            for (int b = 0; b < 8; ++b) {
                o[b] = orig[((size_t)b * 3 + c) * NOUT + idx];
                M = fmaf(o[b], R[b], M);
            }
            float s = 0.0f;
#pragma unroll
            for (int b = 0; b < 8; ++b) {
                float d = o[b] - M;
                s = fmaf(d * d, R[b], s);
            }
            local += s * invT;
        }
    }

    __shared__ float red[4];
    const int lane = threadIdx.x & 63;
    const int wid  = threadIdx.x >> 6;
#pragma unroll
    for (int off = 32; off > 0; off >>= 1)
        local += __shfl_down(local, off);
    if (lane == 0) red[wid] = local;
    __syncthreads();
    if (threadIdx.x == 0)
        partial[blockIdx.x] = (red[0] + red[1]) + (red[2] + red[3]);
}

// ---------------- Kernel 3: deterministic final reduce -------------------
__global__ __launch_bounds__(256) void k_reduce(
    const float* __restrict__ partial, int n, float* __restrict__ out)
{
    float s = 0.0f;
    for (int i = threadIdx.x; i < n; i += 256) s += partial[i];
    __shared__ float red[4];
    const int lane = threadIdx.x & 63;
    const int wid  = threadIdx.x >> 6;
#pragma unroll
    for (int off = 32; off > 0; off >>= 1)
        s += __shfl_down(s, off);
    if (lane == 0) red[wid] = s;
    __syncthreads();
    if (threadIdx.x == 0)
        out[0] = (red[0] + red[1]) + (red[2] + red[3]);
}

extern "C" void kernel_launch(void* const* d_in, const int* in_sizes, int n_in,
                              void* d_out, int out_size, void* d_ws, size_t ws_size,
                              hipStream_t stream) {
    const float* original = (const float*)d_in[0];  // [8,3,550,550]
    const float* loc      = (const float*)d_in[1];  // [8,200,4]
    const float* conf     = (const float*)d_in[2];  // [8,200]
    const float* mask     = (const float*)d_in[3];  // [8,200,32]
    const float* proto    = (const float*)d_in[4];  // [8,138,138,32]
    float* out = (float*)d_out;

    float* fconf   = (float*)d_ws;                                   // 8*19044 f32
    float* partial = (float*)((char*)d_ws + (size_t)8 * NPIX * sizeof(float));

    dim3 g1((NPIX + 63) / 64, 8);                   // 298 x 8 blocks, 4 waves each
    k_finalconf<<<g1, 256, 0, stream>>>(loc, conf, mask, proto, fconf);

    const int nb2 = (NOUT + 255) / 256;             // 1182
    k_variance<<<nb2, 256, 0, stream>>>(original, fconf, partial);

    k_reduce<<<1, 256, 0, stream>>>(partial, nb2, out);
}

// Round 4
// 39.376 us; speedup vs baseline: 2.2259x; 1.0598x over previous
//
#include <hip/hip_runtime.h>
#include <hip/hip_bf16.h>

#define BN 200
#define KK 32
#define NT 13          // 13 n-tiles of 16 priors = 208 (padded, cf=0 for tail)
#define HH 138
#define WW 138
#define HO 550
#define WO 550
#define NPIX (HH*WW)      // 19044
#define NOUT (HO*WO)      // 302500
#define EPS 1e-6f
#define LOG2E 1.4426950408889634f

#if __has_builtin(__builtin_amdgcn_rcpf)
#define RCP(x) __builtin_amdgcn_rcpf(x)
#else
#define RCP(x) (1.0f/(x))
#endif
#if __has_builtin(__builtin_amdgcn_exp2f)
#define EXP2(x) __builtin_amdgcn_exp2f(x)
#else
#define EXP2(x) exp2f(x)
#endif

typedef __attribute__((ext_vector_type(8))) short short8v;   // 8 bf16 (4 VGPRs)
typedef __attribute__((ext_vector_type(4))) float f32x4;     // MFMA acc

static __device__ inline short f2bf(float x) {
    __hip_bfloat16 h = __float2bfloat16(x);   // RNE
    return *reinterpret_cast<short*>(&h);
}

// ---------------- Kernel 0: one-time prep --------------------------------
// bfrag[b][t][l] : B-fragment of mask in MFMA lane order (bf16 x8)
// p4[b][t][j]    : (isx', isy', -cx*isx', -cy*isy'), isx' = C/sx, C=sqrt(ln2e/2)
// cf[b][t][j]    : conf (0 for padded priors)
__global__ __launch_bounds__(256) void k_prep(
    const float* __restrict__ loc,    // [B,200,4]
    const float* __restrict__ conf,   // [B,200]
    const float* __restrict__ mask,   // [B,200,32]
    short8v* __restrict__ bfrag,      // [8*13*64]
    float4* __restrict__ p4,          // [8*13*16]
    float*  __restrict__ cf)          // [8*13*16]
{
    const int idx = blockIdx.x * 256 + threadIdx.x;   // over 8*13*64 = 6656
    if (idx >= 8 * NT * 64) return;
    const int l  = idx & 63;
    const int bt = idx >> 6;
    const int t  = bt % NT;
    const int b  = bt / NT;
    const int n  = t * 16 + (l & 15);
    const int k0 = (l >> 4) * 8;

    short8v v;
#pragma unroll
    for (int j = 0; j < 8; ++j) v[j] = 0;
    if (n < BN) {
        const float4* src = (const float4*)(mask + ((size_t)b * BN + n) * KK + k0);
        float4 u0 = src[0], u1 = src[1];
        v[0] = f2bf(u0.x); v[1] = f2bf(u0.y); v[2] = f2bf(u0.z); v[3] = f2bf(u0.w);
        v[4] = f2bf(u1.x); v[5] = f2bf(u1.y); v[6] = f2bf(u1.z); v[7] = f2bf(u1.w);
    }
    bfrag[idx] = v;

    if (l < 16) {
        float4 pr = {0.f, 0.f, 0.f, 0.f};
        float  cv = 0.f;
        if (n < BN) {
            const float C = sqrtf(0.5f * LOG2E);
            float4 l4 = ((const float4*)loc)[(size_t)b * BN + n];
            float isx = RCP(l4.z) * C;
            float isy = RCP(l4.w) * C;
            pr.x = isx; pr.y = isy;
            pr.z = -l4.x * isx; pr.w = -l4.y * isy;
            cv = conf[(size_t)b * BN + n];
        }
        p4[bt * 16 + (l & 15)] = pr;
        cf[bt * 16 + (l & 15)] = cv;
    }
}

// ---------------- Kernel 1: MFMA sigmoid(proto.mask) * gauss * conf ------
// block = 256 = 4 waves; each wave owns 16 pixels. No LDS, no barrier.
__global__ __launch_bounds__(256) void k_finalconf(
    const float* __restrict__ proto,  // [B,138,138,32]
    const short8v* __restrict__ bfrag,
    const float4* __restrict__ p4,
    const float*  __restrict__ cf,
    float* __restrict__ fconf)        // [B,138,138]
{
    const int b    = blockIdx.y;
    const int tid  = threadIdx.x;
    const int wid  = tid >> 6;
    const int lane = tid & 63;
    const int mbase = blockIdx.x * 64 + wid * 16;

    // A-fragment: lane l holds proto[pix = mbase+(l&15)][k = 8*(l>>4)+j]
    int pa = mbase + (lane & 15);
    if (pa >= NPIX) pa = NPIX - 1;
    const int ka = (lane >> 4) * 8;
    const float4* asrc = (const float4*)(proto + ((size_t)b * NPIX + pa) * KK + ka);
    float4 a0 = asrc[0], a1 = asrc[1];
    short8v afrag;
    afrag[0] = f2bf(a0.x); afrag[1] = f2bf(a0.y); afrag[2] = f2bf(a0.z); afrag[3] = f2bf(a0.w);
    afrag[4] = f2bf(a1.x); afrag[5] = f2bf(a1.y); afrag[6] = f2bf(a1.z); afrag[7] = f2bf(a1.w);

    // C rows this lane accumulates: pixel p_r = mbase + (lane>>4)*4 + r
    float xr[4], yr[4];
    int   pr[4];
#pragma unroll
    for (int r = 0; r < 4; ++r) {
        int p = mbase + (lane >> 4) * 4 + r;
        pr[r] = p;
        int pc = p < NPIX ? p : NPIX - 1;
        int h = pc / WW, w = pc - h * WW;
        xr[r] = (w + 0.5f) * (1.0f / WW);
        yr[r] = (h + 0.5f) * (1.0f / HH);
    }

    const short8v* BF = bfrag + (size_t)b * NT * 64 + lane;
    const float4*  PP = p4 + (size_t)b * NT * 16 + (lane & 15);
    const float*   CV = cf + (size_t)b * NT * 16 + (lane & 15);

    float sum1[4] = {0.f, 0.f, 0.f, 0.f};
    float sum2[4] = {0.f, 0.f, 0.f, 0.f};

#pragma unroll
    for (int t = 0; t < NT; ++t) {
        short8v bf = BF[t * 64];
        float4  pp = PP[t * 16];
        float   cv = CV[t * 16];
        f32x4 c = {0.f, 0.f, 0.f, 0.f};
        c = __builtin_amdgcn_mfma_f32_16x16x32_bf16(afrag, bf, c, 0, 0, 0);
#pragma unroll
        for (int r = 0; r < 4; ++r) {
            const float s  = c[r];
            const float tt = EXP2(-LOG2E * s);                 // exp(-s)
            const float a  = RCP(1.0f + tt);                   // sigmoid
            const float dx = fmaf(xr[r], pp.x, pp.z);
            const float dy = fmaf(yr[r], pp.y, pp.w);
            const float z  = fmaf(dy, dy, dx * dx);
            const float g  = EXP2(-z);                         // gaussian
            const float mc = a * g * cv;
            sum1[r] += mc;
            sum2[r] = fmaf(mc, mc, sum2[r]);
        }
    }

    // reduce over the 16 prior-columns (lane&15 butterfly)
#pragma unroll
    for (int m = 1; m < 16; m <<= 1) {
#pragma unroll
        for (int r = 0; r < 4; ++r) {
            sum1[r] += __shfl_xor(sum1[r], m);
            sum2[r] += __shfl_xor(sum2[r], m);
        }
    }

    const int rsel = lane & 15;
#pragma unroll
    for (int r = 0; r < 4; ++r) {
        if (rsel == r && pr[r] < NPIX)
            fconf[(size_t)b * NPIX + pr[r]] = 1.0f - sum2[r] * RCP(sum1[r] + EPS);
    }
}

// ---------------- Kernel 2: bilinear upsample + weighted variance --------
__global__ __launch_bounds__(256) void k_variance(
    const float* __restrict__ orig,   // [B,3,550,550]
    const float* __restrict__ fconf,  // [B,138,138]
    float* __restrict__ partial)      // [gridDim.x]
{
    const int idx = blockIdx.x * 256 + threadIdx.x;
    float local = 0.0f;

    if (idx < NOUT) {
        const int yo = idx / WO;
        const int xo = idx - yo * WO;
        const float scale = 138.0f / 550.0f;
        float fy = (yo + 0.5f) * scale - 0.5f;
        float fx = (xo + 0.5f) * scale - 0.5f;
        float fy0 = floorf(fy), fx0 = floorf(fx);
        float wy = fy - fy0, wx = fx - fx0;
        int y0 = max(0, min(HH - 1, (int)fy0));
        int y1 = max(0, min(HH - 1, (int)fy0 + 1));
        int x0 = max(0, min(WW - 1, (int)fx0));
        int x1 = max(0, min(WW - 1, (int)fx0 + 1));

        float R[8];
        float T = 0.0f;
#pragma unroll
        for (int b = 0; b < 8; ++b) {
            const float* F = fconf + (size_t)b * NPIX;
            float v00 = F[y0 * WW + x0], v01 = F[y0 * WW + x1];
            float v10 = F[y1 * WW + x0], v11 = F[y1 * WW + x1];
            float v0 = v00 + wx * (v01 - v00);
            float v1 = v10 + wx * (v11 - v10);
            R[b] = v0 + wy * (v1 - v0);
            T += R[b];
        }
        const float invT = RCP(T + EPS);

#pragma unroll
        for (int c = 0; c < 3; ++c) {
            float o[8];
            float M = 0.0f;
#pragma unroll
            for (int b = 0; b < 8; ++b) {
                o[b] = orig[((size_t)b * 3 + c) * NOUT + idx];
                M = fmaf(o[b], R[b], M);
            }
            float s = 0.0f;
#pragma unroll
            for (int b = 0; b < 8; ++b) {
                float d = o[b] - M;
                s = fmaf(d * d, R[b], s);
            }
            local += s * invT;
        }
    }

    __shared__ float red[4];
    const int lane = threadIdx.x & 63;
    const int wid  = threadIdx.x >> 6;
#pragma unroll
    for (int off = 32; off > 0; off >>= 1)
        local += __shfl_down(local, off);
    if (lane == 0) red[wid] = local;
    __syncthreads();
    if (threadIdx.x == 0)
        partial[blockIdx.x] = (red[0] + red[1]) + (red[2] + red[3]);
}

// ---------------- Kernel 3: deterministic final reduce -------------------
__global__ __launch_bounds__(256) void k_reduce(
    const float* __restrict__ partial, int n, float* __restrict__ out)
{
    float s = 0.0f;
    for (int i = threadIdx.x; i < n; i += 256) s += partial[i];
    __shared__ float red[4];
    const int lane = threadIdx.x & 63;
    const int wid  = threadIdx.x >> 6;
#pragma unroll
    for (int off = 32; off > 0; off >>= 1)
        s += __shfl_down(s, off);
    if (lane == 0) red[wid] = s;
    __syncthreads();
    if (threadIdx.x == 0)
        out[0] = (red[0] + red[1]) + (red[2] + red[3]);
}

extern "C" void kernel_launch(void* const* d_in, const int* in_sizes, int n_in,
                              void* d_out, int out_size, void* d_ws, size_t ws_size,
                              hipStream_t stream) {
    const float* original = (const float*)d_in[0];  // [8,3,550,550]
    const float* loc      = (const float*)d_in[1];  // [8,200,4]
    const float* conf     = (const float*)d_in[2];  // [8,200]
    const float* mask     = (const float*)d_in[3];  // [8,200,32]
    const float* proto    = (const float*)d_in[4];  // [8,138,138,32]
    float* out = (float*)d_out;

    const int nb2 = (NOUT + 255) / 256;             // 1182

    char* ws = (char*)d_ws;
    float*   fconf   = (float*)ws;                     ws += (size_t)8 * NPIX * sizeof(float);
    float*   partial = (float*)ws;                     ws += (size_t)nb2 * sizeof(float) + 64;
    short8v* bfrag   = (short8v*)ws;                   ws += (size_t)8 * NT * 64 * sizeof(short8v);
    float4*  p4      = (float4*)ws;                    ws += (size_t)8 * NT * 16 * sizeof(float4);
    float*   cf      = (float*)ws;

    k_prep<<<(8 * NT * 64 + 255) / 256, 256, 0, stream>>>(loc, conf, mask, bfrag, p4, cf);

    dim3 g1((NPIX + 63) / 64, 8);                   // 298 x 8 blocks, 4 waves each
    k_finalconf<<<g1, 256, 0, stream>>>(proto, bfrag, p4, cf, fconf);

    k_variance<<<nb2, 256, 0, stream>>>(original, fconf, partial);

    k_reduce<<<1, 256, 0, stream>>>(partial, nb2, out);
}